// Round 1
// baseline (708.289 us; speedup 1.0000x reference)
//
#include <hip/hip_runtime.h>

// CropAndResize: image (8,256,200,200) fp32, boxes (N,4), box_ind (N,) ->
// out (N,256,14,14) fp32.
// R3 (latency-bound gather -> raise MLP + cache locality):
//  (1) __launch_bounds__(256,6): lift the 28-VGPR straitjacket so unrolled
//      gathers actually stay in flight (~80 VGPR cap, occupancy ~= measured 70%).
//  (2) full unroll-7 of the exactly-49-iteration element loop.
//  (3) per-pixel packed descriptors in LDS: int4{topOff,dR,dB,valid} +
//      float2{ly,lx} -> 2 wide LDS reads/elem instead of 8 scalar reads.
//  (4) chunk-major block order (channel chunks share zero cache lines, so the
//      concurrent working set shrinks 4x) + bijective XCD swizzle so each XCD's
//      private L2 holds one contiguous sorted-slot range (no duplication).

#define CROP_H 14
#define CROP_W 14
#define CROP_HW (CROP_H * CROP_W)           // 196
#define C_DIM 256
#define H_DIM 200
#define W_DIM 200
#define HW (H_DIM * W_DIM)
#define PER_BOX (C_DIM * CROP_HW)           // 50176
#define BLOCK 256
#define CHUNKS 4
#define C_PER (C_DIM / CHUNKS)              // 64 channels per block
#define ELEMS (C_PER * CROP_HW)             // 12544 elements per block
#define ITERS (ELEMS / BLOCK)               // 49 (exact, no tail)
#define NXCD 8

__global__ __launch_bounds__(BLOCK) void sort_boxes_kernel(
    const int* __restrict__ box_ind, int N, int* __restrict__ perm)
{
    __shared__ int cnt[8];
    __shared__ int base[8];
    const int t = threadIdx.x;
    if (t < 8) cnt[t] = 0;
    __syncthreads();
    for (int i = t; i < N; i += BLOCK) atomicAdd(&cnt[box_ind[i]], 1);
    __syncthreads();
    if (t == 0) {
        int run = 0;
        for (int b = 0; b < 8; ++b) { base[b] = run; run += cnt[b]; }
    }
    __syncthreads();
    for (int i = t; i < N; i += BLOCK) {
        const int pos = atomicAdd(&base[box_ind[i]], 1);
        perm[pos] = i;
    }
}

__global__ __launch_bounds__(BLOCK, 6) void crop_and_resize_kernel(
    const float* __restrict__ image,
    const float* __restrict__ boxes,
    const int*   __restrict__ box_ind,
    const int*   __restrict__ perm,
    float*       __restrict__ out,
    int N)
{
    __shared__ int4   s_d[CROP_HW];   // {topOff = ti*W+li, dR = ri-li, dB = (bi-ti)*W, valid}
    __shared__ float2 s_w[CROP_HW];   // {ly, lx}
    __shared__ int s_n, s_b;

    // Bijective XCD swizzle: each XCD gets a contiguous chunk-major range.
    const int nwg = gridDim.x;
    int wgid = blockIdx.x;
    if ((nwg % NXCD) == 0) {
        const int per = nwg / NXCD;
        wgid = (wgid % NXCD) * per + wgid / NXCD;
    }
    // Chunk-major: consecutive wgid -> consecutive sorted slots within a chunk.
    const int chunk = wgid / N;
    const int slot  = wgid - chunk * N;
    const int t     = threadIdx.x;

    if (t == 0) {
        const int n = perm[slot];
        s_n = n;
        s_b = box_ind[n];
    }
    __syncthreads();
    const int n = s_n;

    if (t < CROP_HW) {
        const int iy = t / CROP_W;
        const int ix = t - iy * CROP_W;
        const float y1 = boxes[n * 4 + 0];
        const float x1 = boxes[n * 4 + 1];
        const float y2 = boxes[n * 4 + 2];
        const float x2 = boxes[n * 4 + 3];

        const float hs   = (y2 - y1) * (float)(H_DIM - 1) / (float)(CROP_H - 1);
        const float ws   = (x2 - x1) * (float)(W_DIM - 1) / (float)(CROP_W - 1);
        const float in_y = y1 * (float)(H_DIM - 1) + (float)iy * hs;
        const float in_x = x1 * (float)(W_DIM - 1) + (float)ix * ws;

        const int vy = (in_y >= 0.0f) && (in_y <= (float)(H_DIM - 1));
        const int vx = (in_x >= 0.0f) && (in_x <= (float)(W_DIM - 1));

        const float top  = floorf(in_y);
        const float left = floorf(in_x);
        const float ly   = in_y - top;    // from UNclipped floor (matches ref)
        const float lx   = in_x - left;

        int ti = (int)top;
        ti = min(max(ti, 0), H_DIM - 1);
        const int bi = min(ti + 1, H_DIM - 1);
        int li = (int)left;
        li = min(max(li, 0), W_DIM - 1);
        const int ri = min(li + 1, W_DIM - 1);

        s_d[t] = make_int4(ti * W_DIM + li, ri - li, (bi - ti) * W_DIM, vy & vx);
        s_w[t] = make_float2(ly, lx);
    }
    __syncthreads();

    const float* __restrict__ imgb = image + (size_t)s_b * (C_DIM * HW)
                                           + (size_t)chunk * (C_PER * HW);
    float* __restrict__ outb = out + (size_t)n * PER_BOX + (size_t)chunk * ELEMS;

    #pragma unroll 7
    for (int k = 0; k < ITERS; ++k) {
        const int j = t + k * BLOCK;
        const int c = j / CROP_HW;                 // magic-mul div
        const int p = j - c * CROP_HW;

        const int4   d = s_d[p];                   // one ds_read_b128
        const float2 w = s_w[p];                   // one ds_read_b64

        const float* __restrict__ basec = imgb + (size_t)c * HW + d.x;
        const float tl = basec[0];
        const float tr = basec[d.y];
        const float bl = basec[d.z];
        const float br = basec[d.z + d.y];

        const float top_v = fmaf(tr - tl, w.y, tl);
        const float bot_v = fmaf(br - bl, w.y, bl);
        float v = fmaf(bot_v - top_v, w.x, top_v);
        v = d.w ? v : 0.0f;                        // predicated extrapolation
        outb[j] = v;
    }
}

extern "C" void kernel_launch(void* const* d_in, const int* in_sizes, int n_in,
                              void* d_out, int out_size, void* d_ws, size_t ws_size,
                              hipStream_t stream) {
    const float* image   = (const float*)d_in[0];
    const float* boxes   = (const float*)d_in[1];
    const int*   box_ind = (const int*)d_in[2];
    float*       out     = (float*)d_out;
    int*         perm    = (int*)d_ws;          // N ints of scratch

    const int N = in_sizes[2];  // number of boxes (1000)

    sort_boxes_kernel<<<dim3(1), dim3(BLOCK), 0, stream>>>(box_ind, N, perm);
    crop_and_resize_kernel<<<dim3(N * CHUNKS), dim3(BLOCK), 0, stream>>>(
        image, boxes, box_ind, perm, out, N);
}

// Round 2
// 671.371 us; speedup vs baseline: 1.0550x; 1.0550x over previous
//
#include <hip/hip_runtime.h>

// CropAndResize: image (8,256,200,200) fp32, boxes (N,4), box_ind (N,) ->
// out (N,256,14,14) fp32.
// R4 (force MLP — compiler refuses to create it on its own):
//  Phase-split gather: groups of 7 elements -> issue all 28 global loads
//  back-to-back, then __builtin_amdgcn_sched_barrier(0) fence, then consume.
//  The fence forces >=28 load results live across it -> RA must allocate the
//  registers launch_bounds alone failed to produce (R3: VGPR stayed 32,
//  dur unchanged 370us, every pipe idle -> latency-bound).
//  Kept from R2/R3: counting-sort by image, chunk-major block order,
//  bijective XCD swizzle, packed LDS descriptors.

#define CROP_H 14
#define CROP_W 14
#define CROP_HW (CROP_H * CROP_W)           // 196
#define C_DIM 256
#define H_DIM 200
#define W_DIM 200
#define HW (H_DIM * W_DIM)
#define PER_BOX (C_DIM * CROP_HW)           // 50176
#define BLOCK 256
#define CHUNKS 4
#define C_PER (C_DIM / CHUNKS)              // 64 channels per block
#define ELEMS (C_PER * CROP_HW)             // 12544 elements per block
#define ITERS (ELEMS / BLOCK)               // 49 (exact, no tail)
#define GRP 7                               // 49 = 7 groups of 7
#define NXCD 8

__global__ __launch_bounds__(BLOCK) void sort_boxes_kernel(
    const int* __restrict__ box_ind, int N, int* __restrict__ perm)
{
    __shared__ int cnt[8];
    __shared__ int base[8];
    const int t = threadIdx.x;
    if (t < 8) cnt[t] = 0;
    __syncthreads();
    for (int i = t; i < N; i += BLOCK) atomicAdd(&cnt[box_ind[i]], 1);
    __syncthreads();
    if (t == 0) {
        int run = 0;
        for (int b = 0; b < 8; ++b) { base[b] = run; run += cnt[b]; }
    }
    __syncthreads();
    for (int i = t; i < N; i += BLOCK) {
        const int pos = atomicAdd(&base[box_ind[i]], 1);
        perm[pos] = i;
    }
}

__global__ __launch_bounds__(BLOCK, 6) void crop_and_resize_kernel(
    const float* __restrict__ image,
    const float* __restrict__ boxes,
    const int*   __restrict__ box_ind,
    const int*   __restrict__ perm,
    float*       __restrict__ out,
    int N)
{
    __shared__ int4   s_d[CROP_HW];   // {topOff = ti*W+li, dR = ri-li, dB = (bi-ti)*W, unused}
    __shared__ float4 s_w[CROP_HW];   // {ly, lx, validFloat, unused}
    __shared__ int s_n, s_b;

    // Bijective XCD swizzle: each XCD gets a contiguous chunk-major range.
    const int nwg = gridDim.x;
    int wgid = blockIdx.x;
    if ((nwg % NXCD) == 0) {
        const int per = nwg / NXCD;
        wgid = (wgid % NXCD) * per + wgid / NXCD;
    }
    // Chunk-major: consecutive wgid -> consecutive sorted slots within a chunk.
    const int chunk = wgid / N;
    const int slot  = wgid - chunk * N;
    const int t     = threadIdx.x;

    if (t == 0) {
        const int n = perm[slot];
        s_n = n;
        s_b = box_ind[n];
    }
    __syncthreads();
    const int n = s_n;

    if (t < CROP_HW) {
        const int iy = t / CROP_W;
        const int ix = t - iy * CROP_W;
        const float y1 = boxes[n * 4 + 0];
        const float x1 = boxes[n * 4 + 1];
        const float y2 = boxes[n * 4 + 2];
        const float x2 = boxes[n * 4 + 3];

        const float hs   = (y2 - y1) * (float)(H_DIM - 1) / (float)(CROP_H - 1);
        const float ws   = (x2 - x1) * (float)(W_DIM - 1) / (float)(CROP_W - 1);
        const float in_y = y1 * (float)(H_DIM - 1) + (float)iy * hs;
        const float in_x = x1 * (float)(W_DIM - 1) + (float)ix * ws;

        const int vy = (in_y >= 0.0f) && (in_y <= (float)(H_DIM - 1));
        const int vx = (in_x >= 0.0f) && (in_x <= (float)(W_DIM - 1));

        const float top  = floorf(in_y);
        const float left = floorf(in_x);
        const float ly   = in_y - top;    // from UNclipped floor (matches ref)
        const float lx   = in_x - left;

        int ti = (int)top;
        ti = min(max(ti, 0), H_DIM - 1);
        const int bi = min(ti + 1, H_DIM - 1);
        int li = (int)left;
        li = min(max(li, 0), W_DIM - 1);
        const int ri = min(li + 1, W_DIM - 1);

        s_d[t] = make_int4(ti * W_DIM + li, ri - li, (bi - ti) * W_DIM, 0);
        s_w[t] = make_float4(ly, lx, (vy & vx) ? 1.0f : 0.0f, 0.0f);
    }
    __syncthreads();

    const float* __restrict__ imgb = image + (size_t)s_b * (C_DIM * HW)
                                           + (size_t)chunk * (C_PER * HW);
    float* __restrict__ outb = out + (size_t)n * PER_BOX + (size_t)chunk * ELEMS;

    #pragma unroll
    for (int g = 0; g < ITERS / GRP; ++g) {
        float tl[GRP], tr[GRP], bl[GRP], br[GRP];

        // Phase A: issue all 28 gathers of this group back-to-back.
        #pragma unroll
        for (int u = 0; u < GRP; ++u) {
            const int j = t + (g * GRP + u) * BLOCK;
            const int c = j / CROP_HW;                 // magic-mul div
            const int p = j - c * CROP_HW;
            const int4 d = s_d[p];                     // one ds_read_b128
            const float* __restrict__ bc = imgb + (size_t)c * HW + d.x;
            tl[u] = bc[0];
            tr[u] = bc[d.y];
            bl[u] = bc[d.z];
            br[u] = bc[d.z + d.y];
        }

        // Fence: loads may NOT sink past this point -> 28 results stay live,
        // waitcnt is batched, MLP is structural not heuristic.
        __builtin_amdgcn_sched_barrier(0);

        // Phase C: consume + store.
        #pragma unroll
        for (int u = 0; u < GRP; ++u) {
            const int j = t + (g * GRP + u) * BLOCK;
            const int c = j / CROP_HW;
            const int p = j - c * CROP_HW;
            const float4 w = s_w[p];                   // {ly, lx, vf, -}
            const float top_v = fmaf(tr[u] - tl[u], w.y, tl[u]);
            const float bot_v = fmaf(br[u] - bl[u], w.y, bl[u]);
            float v = fmaf(bot_v - top_v, w.x, top_v);
            outb[j] = v * w.z;                         // extrapolation -> *0.0f
        }
    }
}

extern "C" void kernel_launch(void* const* d_in, const int* in_sizes, int n_in,
                              void* d_out, int out_size, void* d_ws, size_t ws_size,
                              hipStream_t stream) {
    const float* image   = (const float*)d_in[0];
    const float* boxes   = (const float*)d_in[1];
    const int*   box_ind = (const int*)d_in[2];
    float*       out     = (float*)d_out;
    int*         perm    = (int*)d_ws;          // N ints of scratch

    const int N = in_sizes[2];  // number of boxes (1000)

    sort_boxes_kernel<<<dim3(1), dim3(BLOCK), 0, stream>>>(box_ind, N, perm);
    crop_and_resize_kernel<<<dim3(N * CHUNKS), dim3(BLOCK), 0, stream>>>(
        image, boxes, box_ind, perm, out, N);
}